// Round 1
// baseline (49.066 us; speedup 1.0000x reference)
//
#include <hip/hip_runtime.h>
#include <math.h>

#define KNBR 20
#define BLK  128

// SH normalization constants nlm = sqrt((2l+1)/(4pi) * (l-m)!/(l+m)!)
#define N20 0.6307831305050401f
#define N21 0.2575161346821503f
#define N22 0.1287580673410752f
#define N40 0.8462843753216345f
#define N41 0.1892349391526903f
#define N42 0.0446031029038193f
#define N43 0.0119206816337750f
#define N44 0.0042145970709046f
#define N60 1.0171071264927600f
#define N61 0.1569430465425941f
#define N62 0.0248148700528581f
#define N63 0.0041358126086450f
#define N64 0.0007550926197968f
#define N65 0.0001609862874555f
#define N66 0.0000464727381991f

#define THETA_T  1.9106332362490186f   // 0.6081734479693927 * pi
#define INV_SIG  4.7746482927568605f   // 1 / (12 deg in rad)
#define PI_F     3.14159265358979323846f

__global__ __launch_bounds__(BLK)
void op_kernel(const float* __restrict__ pos,
               const int*   __restrict__ aidx,
               const int*   __restrict__ nidx,
               const int*   __restrict__ vmsk,
               float*       __restrict__ out,
               int M)
{
    __shared__ float su[3 * KNBR * BLK];   // [d][slot][tid], 30720 B
    const int tid = threadIdx.x;
    const int i = blockIdx.x * BLK + tid;
    if (i >= M) return;

    float cx, cy, cz;
    {
        const int a = aidx[i];
        cx = pos[3 * a + 0];
        cy = pos[3 * a + 1];
        cz = pos[3 * a + 2];
    }

    // accumulators: re/im per (l,m); im for m=0 is identically 0
    float re20 = 0.f, re21 = 0.f, im21 = 0.f, re22 = 0.f, im22 = 0.f;
    float re40 = 0.f, re41 = 0.f, im41 = 0.f, re42 = 0.f, im42 = 0.f;
    float re43 = 0.f, im43 = 0.f, re44 = 0.f, im44 = 0.f;
    float re60 = 0.f, re61 = 0.f, im61 = 0.f, re62 = 0.f, im62 = 0.f;
    float re63 = 0.f, im63 = 0.f, re64 = 0.f, im64 = 0.f;
    float re65 = 0.f, im65 = 0.f, re66 = 0.f, im66 = 0.f;
    int cnt = 0;

    auto process = [&](int nj, int valid) {
        if (valid > 0) {
            const float px = pos[3 * nj + 0];
            const float py = pos[3 * nj + 1];
            const float pz = pos[3 * nj + 2];
            const float vx = px - cx, vy = py - cy, vz = pz - cz;
            const float dist = sqrtf(vx * vx + vy * vy + vz * vz);
            const float inv = 1.0f / (dist + 1e-10f);
            const float ux = vx * inv, uy = vy * inv, uz = vz * inv;

            su[(0 * KNBR + cnt) * BLK + tid] = ux;
            su[(1 * KNBR + cnt) * BLK + tid] = uy;
            su[(2 * KNBR + cnt) * BLK + tid] = uz;
            ++cnt;

            const float x  = fminf(fmaxf(uz, -1.f + 1e-7f), 1.f - 1e-7f);
            const float x2 = x * x, x3 = x2 * x, x4 = x2 * x2, x5 = x3 * x2, x6 = x3 * x3;
            const float ss = 1.f - x2;            // sin^2(theta)
            const float s  = sqrtf(ss);
            const float s3 = ss * s, s4 = ss * ss, s5 = s4 * s, s6 = s4 * ss;

            const float rxy = sqrtf(ux * ux + uy * uy);
            float c1, p1;
            if (rxy > 1e-20f) {
                const float ir = 1.f / rxy;
                c1 = ux * ir; p1 = uy * ir;       // cos(phi), sin(phi)
            } else {
                c1 = 1.f; p1 = 0.f;               // atan2(0,0) = 0
            }
            const float tc = 2.f * c1;
            const float c2 = tc * c1 - 1.f,  p2 = tc * p1;
            const float c3 = tc * c2 - c1,   p3 = tc * p2 - p1;
            const float c4 = tc * c3 - c2,   p4 = tc * p3 - p2;
            const float c5 = tc * c4 - c3,   p5 = tc * p4 - p3;
            const float c6 = tc * c5 - c4,   p6 = tc * p5 - p4;

            float P;
            // l = 2
            P = N20 * (0.5f * (3.f * x2 - 1.f));                        re20 += P;
            P = N21 * (-3.f * x * s);                                    re21 += P * c1; im21 += P * p1;
            P = N22 * (3.f * ss);                                        re22 += P * c2; im22 += P * p2;
            // l = 4
            P = N40 * (0.125f * (35.f * x4 - 30.f * x2 + 3.f));          re40 += P;
            P = N41 * (-2.5f * (7.f * x3 - 3.f * x) * s);                re41 += P * c1; im41 += P * p1;
            P = N42 * (7.5f * (7.f * x2 - 1.f) * ss);                    re42 += P * c2; im42 += P * p2;
            P = N43 * (-105.f * x * s3);                                 re43 += P * c3; im43 += P * p3;
            P = N44 * (105.f * s4);                                      re44 += P * c4; im44 += P * p4;
            // l = 6
            P = N60 * ((231.f * x6 - 315.f * x4 + 105.f * x2 - 5.f) * 0.0625f);  re60 += P;
            P = N61 * (-2.625f * (33.f * x5 - 30.f * x3 + 5.f * x) * s); re61 += P * c1; im61 += P * p1;
            P = N62 * (13.125f * (33.f * x4 - 18.f * x2 + 1.f) * ss);    re62 += P * c2; im62 += P * p2;
            P = N63 * (-157.5f * (11.f * x3 - 3.f * x) * s3);            re63 += P * c3; im63 += P * p3;
            P = N64 * (472.5f * (11.f * x2 - 1.f) * s4);                 re64 += P * c4; im64 += P * p4;
            P = N65 * (-10395.f * x * s5);                               re65 += P * c5; im65 += P * p5;
            P = N66 * (10395.f * s6);                                    re66 += P * c6; im66 += P * p6;
        }
    };

    {
        const int4* n4 = reinterpret_cast<const int4*>(nidx + (size_t)i * KNBR);
        const int4* m4 = reinterpret_cast<const int4*>(vmsk + (size_t)i * KNBR);
        #pragma unroll
        for (int g = 0; g < KNBR / 4; ++g) {
            const int4 nn = n4[g];
            const int4 mm = m4[g];
            process(nn.x, mm.x);
            process(nn.y, mm.y);
            process(nn.z, mm.z);
            process(nn.w, mm.w);
        }
    }

    const float cn = (float)cnt;
    const float invnb = 1.f / fmaxf(cn, 1.f);

    // q_l = (1/nb) * sqrt(4pi/(2l+1) * sum_m w * (re^2 + im^2))
    const float S2 = re20 * re20
                   + 2.f * (re21 * re21 + im21 * im21 + re22 * re22 + im22 * im22);
    const float S4 = re40 * re40
                   + 2.f * (re41 * re41 + im41 * im41 + re42 * re42 + im42 * im42
                          + re43 * re43 + im43 * im43 + re44 * re44 + im44 * im44);
    const float S6 = re60 * re60
                   + 2.f * (re61 * re61 + im61 * im61 + re62 * re62 + im62 * im62
                          + re63 * re63 + im63 * im63 + re64 * re64 + im64 * im64
                          + re65 * re65 + im65 * im65 + re66 * re66 + im66 * im66);
    const float q2 = invnb * sqrtf(2.5132741228718345f * S2);  // 4pi/5
    const float q4 = invnb * sqrtf(1.3962634015954636f * S4);  // 4pi/9
    const float q6 = invnb * sqrtf(0.9666438933772774f * S6);  // 4pi/13

    // tetrahedral OP over valid-pair angles (k<l doubled)
    float gsum = 0.f;
    for (int a = 0; a < cnt; ++a) {
        const float ax = su[(0 * KNBR + a) * BLK + tid];
        const float ay = su[(1 * KNBR + a) * BLK + tid];
        const float az = su[(2 * KNBR + a) * BLK + tid];
        for (int b = a + 1; b < cnt; ++b) {
            const float bx = su[(0 * KNBR + b) * BLK + tid];
            const float by = su[(1 * KNBR + b) * BLK + tid];
            const float bz = su[(2 * KNBR + b) * BLK + tid];
            float d = ax * bx + ay * by + az * bz;
            d = fminf(fmaxf(d, -1.f + 1e-7f), 1.f - 1e-7f);
            // branchless A&S 4.4.45 acos, |err| <= ~6.8e-5 rad
            const float ad = fabsf(d);
            const float pq = (((-0.0187293f * ad + 0.0742610f) * ad - 0.2121144f) * ad
                              + 1.5707288f) * sqrtf(1.f - ad);
            const float ang = (d >= 0.f) ? pq : (PI_F - pq);
            const float t = (ang - THETA_T) * INV_SIG;
            gsum += __expf(-0.5f * t * t);
        }
    }
    const float tet = (2.f * gsum) / fmaxf(cn * (cn - 1.f), 1.f);

    out[0 * M + i] = cn;
    out[1 * M + i] = tet;
    out[2 * M + i] = q2;
    out[3 * M + i] = q4;
    out[4 * M + i] = q6;
}

extern "C" void kernel_launch(void* const* d_in, const int* in_sizes, int n_in,
                              void* d_out, int out_size, void* d_ws, size_t ws_size,
                              hipStream_t stream) {
    const float* pos  = (const float*)d_in[0];
    const int*   aidx = (const int*)d_in[1];
    const int*   nidx = (const int*)d_in[2];
    const int*   vmsk = (const int*)d_in[3];
    float* out = (float*)d_out;
    const int M = in_sizes[1];
    const int grid = (M + BLK - 1) / BLK;
    op_kernel<<<grid, BLK, 0, stream>>>(pos, aidx, nidx, vmsk, out, M);
}

// Round 2
// 29.333 us; speedup vs baseline: 1.6728x; 1.6728x over previous
//
#include <hip/hip_runtime.h>
#include <math.h>

#define KNBR 20
#define BLK  256
#define APB  64           // atoms per block (BLK/4)
#define APB1 65           // padded atom stride (bank = (slot+atom)%32)

// SH normalization constants nlm = sqrt((2l+1)/(4pi) * (l-m)!/(l+m)!)
#define N20 0.6307831305050401f
#define N21 0.2575161346821503f
#define N22 0.1287580673410752f
#define N40 0.8462843753216345f
#define N41 0.1892349391526903f
#define N42 0.0446031029038193f
#define N43 0.0119206816337750f
#define N44 0.0042145970709046f
#define N60 1.0171071264927600f
#define N61 0.1569430465425941f
#define N62 0.0248148700528581f
#define N63 0.0041358126086450f
#define N64 0.0007550926197968f
#define N65 0.0001609862874555f
#define N66 0.0000464727381991f

#define THETA_T  1.9106332362490186f   // 0.6081734479693927 * pi
#define INV_SIG  4.7746482927568605f   // 1 / (12 deg in rad)
#define PI_F     3.14159265358979323846f

__global__ __launch_bounds__(BLK)
void op_kernel(const float* __restrict__ pos,
               const int*   __restrict__ aidx,
               const int*   __restrict__ nidx,
               const int*   __restrict__ vmsk,
               float*       __restrict__ out,
               int M)
{
    __shared__ float su[3 * KNBR * APB1];   // [d][slot][atom], 15600 B
    const int tid  = threadIdx.x;
    const int q    = tid & 3;               // lane within quad
    const int al   = tid >> 2;              // atom-local index 0..63
    const int i    = blockIdx.x * APB + al;
    if (i >= M) return;
    const int lane  = tid & 63;
    const int qbase = lane & ~3;

    float cx, cy, cz;
    {
        const int a = aidx[i];
        cx = pos[3 * a + 0];
        cy = pos[3 * a + 1];
        cz = pos[3 * a + 2];
    }

    // my 5 neighbor slots: int4 at q*4 plus scalar at 16+q
    const size_t row = (size_t)i * KNBR;
    const int4 nn = *reinterpret_cast<const int4*>(nidx + row + q * 4);
    const int4 mm = *reinterpret_cast<const int4*>(vmsk + row + q * 4);
    const int  nE = nidx[row + 16 + q];
    const int  mE = vmsk[row + 16 + q];

    int cntLoc = (mm.x > 0) + (mm.y > 0) + (mm.z > 0) + (mm.w > 0) + (mE > 0);

    // quad exclusive scan + total (4 shuffles)
    int off = 0, total = 0;
    {
        int c;
        c = __shfl(cntLoc, qbase + 0); total += c; if (q > 0) off += c;
        c = __shfl(cntLoc, qbase + 1); total += c; if (q > 1) off += c;
        c = __shfl(cntLoc, qbase + 2); total += c; if (q > 2) off += c;
        c = __shfl(cntLoc, qbase + 3); total += c;
    }

    float re20 = 0.f, re21 = 0.f, im21 = 0.f, re22 = 0.f, im22 = 0.f;
    float re40 = 0.f, re41 = 0.f, im41 = 0.f, re42 = 0.f, im42 = 0.f;
    float re43 = 0.f, im43 = 0.f, re44 = 0.f, im44 = 0.f;
    float re60 = 0.f, re61 = 0.f, im61 = 0.f, re62 = 0.f, im62 = 0.f;
    float re63 = 0.f, im63 = 0.f, re64 = 0.f, im64 = 0.f;
    float re65 = 0.f, im65 = 0.f, re66 = 0.f, im66 = 0.f;

    float* col = su + al;

    auto process = [&](int nj, int valid) {
        if (valid > 0) {
            const float px = pos[3 * nj + 0];
            const float py = pos[3 * nj + 1];
            const float pz = pos[3 * nj + 2];
            const float vx = px - cx, vy = py - cy, vz = pz - cz;
            const float d2 = vx * vx + vy * vy + vz * vz;
            const float inv = 1.0f / (sqrtf(d2) + 1e-10f);
            const float ux = vx * inv, uy = vy * inv, uz = vz * inv;

            col[(0 * KNBR + off) * APB1] = ux;
            col[(1 * KNBR + off) * APB1] = uy;
            col[(2 * KNBR + off) * APB1] = uz;
            ++off;

            const float x  = fminf(fmaxf(uz, -1.f + 1e-7f), 1.f - 1e-7f);
            const float x2 = x * x, x3 = x2 * x, x4 = x2 * x2, x5 = x3 * x2, x6 = x3 * x3;
            const float ss = 1.f - x2;
            const float s  = sqrtf(ss);
            const float s3 = ss * s, s4 = ss * ss, s5 = s4 * s, s6 = s4 * ss;

            const float rxy2 = ux * ux + uy * uy;
            float c1, p1;
            if (rxy2 > 1e-30f) {
                const float ir = rsqrtf(rxy2);
                c1 = ux * ir; p1 = uy * ir;
            } else {
                c1 = 1.f; p1 = 0.f;
            }
            const float tc = 2.f * c1;
            const float c2 = tc * c1 - 1.f,  p2 = tc * p1;
            const float c3 = tc * c2 - c1,   p3 = tc * p2 - p1;
            const float c4 = tc * c3 - c2,   p4 = tc * p3 - p2;
            const float c5 = tc * c4 - c3,   p5 = tc * p4 - p3;
            const float c6 = tc * c5 - c4,   p6 = tc * p5 - p4;

            float P;
            P = N20 * (0.5f * (3.f * x2 - 1.f));                         re20 += P;
            P = N21 * (-3.f * x * s);                                    re21 += P * c1; im21 += P * p1;
            P = N22 * (3.f * ss);                                        re22 += P * c2; im22 += P * p2;
            P = N40 * (0.125f * (35.f * x4 - 30.f * x2 + 3.f));          re40 += P;
            P = N41 * (-2.5f * (7.f * x3 - 3.f * x) * s);                re41 += P * c1; im41 += P * p1;
            P = N42 * (7.5f * (7.f * x2 - 1.f) * ss);                    re42 += P * c2; im42 += P * p2;
            P = N43 * (-105.f * x * s3);                                 re43 += P * c3; im43 += P * p3;
            P = N44 * (105.f * s4);                                      re44 += P * c4; im44 += P * p4;
            P = N60 * ((231.f * x6 - 315.f * x4 + 105.f * x2 - 5.f) * 0.0625f); re60 += P;
            P = N61 * (-2.625f * (33.f * x5 - 30.f * x3 + 5.f * x) * s); re61 += P * c1; im61 += P * p1;
            P = N62 * (13.125f * (33.f * x4 - 18.f * x2 + 1.f) * ss);    re62 += P * c2; im62 += P * p2;
            P = N63 * (-157.5f * (11.f * x3 - 3.f * x) * s3);            re63 += P * c3; im63 += P * p3;
            P = N64 * (472.5f * (11.f * x2 - 1.f) * s4);                 re64 += P * c4; im64 += P * p4;
            P = N65 * (-10395.f * x * s5);                               re65 += P * c5; im65 += P * p5;
            P = N66 * (10395.f * s6);                                    re66 += P * c6; im66 += P * p6;
        }
    };

    process(nn.x, mm.x);
    process(nn.y, mm.y);
    process(nn.z, mm.z);
    process(nn.w, mm.w);
    process(nE,  mE);

    // pair loop: lane q takes b = a+1+q, a+5+q, ... (same-wave LDS RAW, no barrier)
    float gsum = 0.f;
    for (int a = 0; a < total - 1; ++a) {
        const float ax = col[(0 * KNBR + a) * APB1];
        const float ay = col[(1 * KNBR + a) * APB1];
        const float az = col[(2 * KNBR + a) * APB1];
        for (int b = a + 1 + q; b < total; b += 4) {
            const float bx = col[(0 * KNBR + b) * APB1];
            const float by = col[(1 * KNBR + b) * APB1];
            const float bz = col[(2 * KNBR + b) * APB1];
            float d = ax * bx + ay * by + az * bz;
            d = fminf(fmaxf(d, -1.f + 1e-7f), 1.f - 1e-7f);
            const float ad = fabsf(d);
            const float pq = (((-0.0187293f * ad + 0.0742610f) * ad - 0.2121144f) * ad
                              + 1.5707288f) * sqrtf(1.f - ad);
            const float ang = (d >= 0.f) ? pq : (PI_F - pq);
            const float t = (ang - THETA_T) * INV_SIG;
            gsum += __expf(-0.5f * t * t);
        }
    }

    // quad butterfly reduction (compiles to DPP quad_perm)
#define RED(v) { v += __shfl_xor(v, 1); v += __shfl_xor(v, 2); }
    RED(re20) RED(re21) RED(im21) RED(re22) RED(im22)
    RED(re40) RED(re41) RED(im41) RED(re42) RED(im42)
    RED(re43) RED(im43) RED(re44) RED(im44)
    RED(re60) RED(re61) RED(im61) RED(re62) RED(im62)
    RED(re63) RED(im63) RED(re64) RED(im64)
    RED(re65) RED(im65) RED(re66) RED(im66)
    RED(gsum)
#undef RED

    const float cn = (float)total;
    const float invnb = 1.f / fmaxf(cn, 1.f);

    const float S2 = re20 * re20
                   + 2.f * (re21 * re21 + im21 * im21 + re22 * re22 + im22 * im22);
    const float S4 = re40 * re40
                   + 2.f * (re41 * re41 + im41 * im41 + re42 * re42 + im42 * im42
                          + re43 * re43 + im43 * im43 + re44 * re44 + im44 * im44);
    const float S6 = re60 * re60
                   + 2.f * (re61 * re61 + im61 * im61 + re62 * re62 + im62 * im62
                          + re63 * re63 + im63 * im63 + re64 * re64 + im64 * im64
                          + re65 * re65 + im65 * im65 + re66 * re66 + im66 * im66);
    const float q2v = invnb * sqrtf(2.5132741228718345f * S2);  // 4pi/5
    const float q4v = invnb * sqrtf(1.3962634015954636f * S4);  // 4pi/9
    const float q6v = invnb * sqrtf(0.9666438933772774f * S6);  // 4pi/13
    const float tet = (2.f * gsum) / fmaxf(cn * (cn - 1.f), 1.f);

    if (q == 0)      { out[0 * M + i] = cn;  out[4 * M + i] = q6v; }
    else if (q == 1) { out[1 * M + i] = tet; }
    else if (q == 2) { out[2 * M + i] = q2v; }
    else             { out[3 * M + i] = q4v; }
}

extern "C" void kernel_launch(void* const* d_in, const int* in_sizes, int n_in,
                              void* d_out, int out_size, void* d_ws, size_t ws_size,
                              hipStream_t stream) {
    const float* pos  = (const float*)d_in[0];
    const int*   aidx = (const int*)d_in[1];
    const int*   nidx = (const int*)d_in[2];
    const int*   vmsk = (const int*)d_in[3];
    float* out = (float*)d_out;
    const int M = in_sizes[1];
    const int grid = (M + APB - 1) / APB;
    op_kernel<<<grid, BLK, 0, stream>>>(pos, aidx, nidx, vmsk, out, M);
}

// Round 3
// 26.846 us; speedup vs baseline: 1.8277x; 1.0926x over previous
//
#include <hip/hip_runtime.h>
#include <math.h>

#define KNBR 20
#define BLK  256
#define APB  32           // atoms per block (BLK/8)
#define SST  33           // slot stride in float4 units (keeps 4-bank groups spread)
#define NSL  23           // 20 real slots + 3 dump slots for invalid writes

#define THETA_T  1.9106332362490186f   // 0.6081734479693927 * pi
#define INV_SIG  4.7746482927568605f   // 1 / (12 deg in rad)
#define PI_F     3.14159265358979323846f

__global__ __launch_bounds__(BLK)
void op_kernel(const float* __restrict__ pos,
               const int*   __restrict__ aidx,
               const int*   __restrict__ nidx,
               const int*   __restrict__ vmsk,
               float*       __restrict__ out,
               int M)
{
    __shared__ float4 su[NSL * SST];        // 12144 B
    const int tid   = threadIdx.x;
    const int r     = tid & 7;              // lane within octet
    const int al    = tid >> 3;             // atom-local 0..31
    const int i     = blockIdx.x * APB + al;
    if (i >= M) return;
    const int lane  = tid & 63;
    const int obase = lane & ~7;

    float cx, cy, cz;
    { const int a = aidx[i]; cx = pos[3*a]; cy = pos[3*a+1]; cz = pos[3*a+2]; }

    // my 3 neighbor slots: r, r+8, and (r<4 ? 16+r : masked)
    const size_t row = (size_t)i * KNBR;
    const int n0 = nidx[row + r];
    const int n1 = nidx[row + r + 8];
    const int n2 = nidx[row + 16 + (r & 3)];
    const int m0 = vmsk[row + r] != 0;
    const int m1 = vmsk[row + r + 8] != 0;
    const int m2 = (r < 4) && (vmsk[row + 16 + (r & 3)] != 0);

    // all 9 gathers issued up-front (overlapped latency)
    const float q0x = pos[3*n0], q0y = pos[3*n0+1], q0z = pos[3*n0+2];
    const float q1x = pos[3*n1], q1y = pos[3*n1+1], q1z = pos[3*n1+2];
    const float q2x = pos[3*n2], q2y = pos[3*n2+1], q2z = pos[3*n2+2];

    // octet exclusive scan + total
    const int cntLoc = m0 + m1 + m2;
    int off = 0, total = 0;
    #pragma unroll
    for (int k = 0; k < 8; ++k) {
        const int c = __shfl(cntLoc, obase + k);
        total += c;
        if (r > k) off += c;
    }

    float re20=0.f, re21=0.f, im21=0.f, re22=0.f, im22=0.f;
    float re40=0.f, re41=0.f, im41=0.f, re42=0.f, im42=0.f;
    float re43=0.f, im43=0.f, re44=0.f, im44=0.f;
    float re60=0.f, re61=0.f, im61=0.f, re62=0.f, im62=0.f;
    float re63=0.f, im63=0.f, re64=0.f, im64=0.f;
    float re65=0.f, im65=0.f, re66=0.f, im66=0.f;

    auto sh = [&](float px, float py, float pz, int mi, int dump) {
        const float mk = (float)mi;
        const float vx = px - cx, vy = py - cy, vz = pz - cz;
        const float d2 = fmaf(vx, vx, fmaf(vy, vy, vz * vz));
        const float inv = __builtin_amdgcn_rcpf(sqrtf(d2) + 1e-10f);
        const float ux = vx * inv, uy = vy * inv, uz = vz * inv;

        const int slot = mi ? off : dump;
        su[slot * SST + al] = make_float4(ux, uy, uz, 0.f);
        off += mi;

        const float x = uz, x2 = x * x;
        // w_m = (ux + i uy)^m  (masked: kills all m>=1 terms when invalid)
        const float w1r = ux * mk, w1i = uy * mk;
        const float w2r = fmaf(w1r, w1r, -(w1i * w1i)), w2i = 2.f * (w1r * w1i);
        const float w3r = fmaf(w2r, w1r, -(w2i * w1i)), w3i = fmaf(w2r, w1i, w2i * w1r);
        const float w4r = fmaf(w3r, w1r, -(w3i * w1i)), w4i = fmaf(w3r, w1i, w3i * w1r);
        const float w5r = fmaf(w4r, w1r, -(w4i * w1i)), w5i = fmaf(w4r, w1i, w4i * w1r);
        const float w6r = fmaf(w5r, w1r, -(w5i * w1i)), w6i = fmaf(w5r, w1i, w5i * w1r);

        float P;
        // m = 0  (needs explicit mask)
        P = fmaf(0.94617470f, x2, -0.31539157f);
        re20 = fmaf(P, mk, re20);
        P = fmaf(fmaf(3.70249414f, x2, -3.17356641f), x2, 0.31735664f);
        re40 = fmaf(P, mk, re40);
        P = fmaf(fmaf(fmaf(14.6844843f, x2, -20.0242968f), x2, 6.67476559f), x2, -0.31784598f);
        re60 = fmaf(P, mk, re60);
        // m = 1
        P = -0.77254840f * x;
        re21 = fmaf(P, w1r, re21); im21 = fmaf(P, w1i, im21);
        P = x * fmaf(-3.31161144f, x2, 1.41926204f);
        re41 = fmaf(P, w1r, re41); im41 = fmaf(P, w1i, im41);
        P = x * fmaf(fmaf(-13.5951914f, x2, 12.3592649f), x2, -2.05987749f);
        re61 = fmaf(P, w1r, re61); im61 = fmaf(P, w1i, im61);
        // m = 2
        re22 = fmaf(0.38627420f, w2r, re22); im22 = fmaf(0.38627420f, w2i, im22);
        P = fmaf(2.34166290f, x2, -0.33452327f);
        re42 = fmaf(P, w2r, re42); im42 = fmaf(P, w2i, im42);
        P = fmaf(fmaf(10.7479410f, x2, -5.86251329f), x2, 0.32569518f);
        re62 = fmaf(P, w2r, re62); im62 = fmaf(P, w2i, im62);
        // m = 3
        P = -1.25167160f * x;
        re43 = fmaf(P, w3r, re43); im43 = fmaf(P, w3i, im43);
        P = x * fmaf(-7.16529533f, x2, 1.95417145f);
        re63 = fmaf(P, w3r, re63); im63 = fmaf(P, w3i, im63);
        // m = 4
        re44 = fmaf(0.44253269f, w4r, re44); im44 = fmaf(0.44253269f, w4i, im44);
        P = fmaf(3.92459379f, x2, -0.35678125f);
        re64 = fmaf(P, w4r, re64); im64 = fmaf(P, w4i, im64);
        // m = 5
        P = -1.67345246f * x;
        re65 = fmaf(P, w5r, re65); im65 = fmaf(P, w5i, im65);
        // m = 6
        re66 = fmaf(0.48308411f, w6r, re66); im66 = fmaf(0.48308411f, w6i, im66);
    };

    sh(q0x, q0y, q0z, m0, 20);
    sh(q1x, q1y, q1z, m1, 21);
    sh(q2x, q2y, q2z, m2, 22);

    // reduce SH accumulators over the octet NOW so only S2/S4/S6 stay live
#define RED(v) { v += __shfl_xor(v,1); v += __shfl_xor(v,2); v += __shfl_xor(v,4); }
    RED(re20) RED(re21) RED(im21) RED(re22) RED(im22)
    RED(re40) RED(re41) RED(im41) RED(re42) RED(im42)
    RED(re43) RED(im43) RED(re44) RED(im44)
    RED(re60) RED(re61) RED(im61) RED(re62) RED(im62)
    RED(re63) RED(im63) RED(re64) RED(im64)
    RED(re65) RED(im65) RED(re66) RED(im66)

    const float S2 = fmaf(re20, re20,
                     2.f * (fmaf(re21,re21, fmaf(im21,im21, fmaf(re22,re22, im22*im22)))));
    const float S4 = fmaf(re40, re40,
                     2.f * (fmaf(re41,re41, fmaf(im41,im41, fmaf(re42,re42, fmaf(im42,im42,
                            fmaf(re43,re43, fmaf(im43,im43, fmaf(re44,re44, im44*im44)))))))));
    const float S6 = fmaf(re60, re60,
                     2.f * (fmaf(re61,re61, fmaf(im61,im61, fmaf(re62,re62, fmaf(im62,im62,
                            fmaf(re63,re63, fmaf(im63,im63, fmaf(re64,re64, fmaf(im64,im64,
                            fmaf(re65,re65, fmaf(im65,im65, fmaf(re66,re66, im66*im66)))))))))))));

    // flat triangular pair loop, strided by octet lane, 2-way unrolled
    const int npairs = (total * (total - 1)) >> 1;
    float gsum = 0.f;
    for (int p = r; p < npairs; p += 16) {
        const int pb = p + 8;
        const int v2 = pb < npairs;
        const int pc = v2 ? pb : p;

        const float fa = (float)p;
        const int  ja = (int)((1.f + sqrtf(fmaf(8.f, fa, 1.f))) * 0.5f);
        const int  ia = p - ((ja * (ja - 1)) >> 1);
        const float fb = (float)pc;
        const int  jb = (int)((1.f + sqrtf(fmaf(8.f, fb, 1.f))) * 0.5f);
        const int  ib = pc - ((jb * (jb - 1)) >> 1);

        const float4 A1 = su[ia * SST + al];
        const float4 B1 = su[ja * SST + al];
        const float4 A2 = su[ib * SST + al];
        const float4 B2 = su[jb * SST + al];

        float d1 = fmaf(A1.x, B1.x, fmaf(A1.y, B1.y, A1.z * B1.z));
        float d2v = fmaf(A2.x, B2.x, fmaf(A2.y, B2.y, A2.z * B2.z));
        d1  = fminf(fmaxf(d1,  -0.9999999f), 0.9999999f);
        d2v = fminf(fmaxf(d2v, -0.9999999f), 0.9999999f);

        const float a1 = fabsf(d1);
        const float pq1 = fmaf(fmaf(fmaf(-0.0187293f, a1, 0.0742610f), a1, -0.2121144f), a1,
                               1.5707288f) * sqrtf(1.f - a1);
        const float an1 = (d1 >= 0.f) ? pq1 : PI_F - pq1;
        const float t1 = (an1 - THETA_T) * INV_SIG;
        gsum += __expf(-0.5f * t1 * t1);

        const float a2 = fabsf(d2v);
        const float pq2 = fmaf(fmaf(fmaf(-0.0187293f, a2, 0.0742610f), a2, -0.2121144f), a2,
                               1.5707288f) * sqrtf(1.f - a2);
        const float an2 = (d2v >= 0.f) ? pq2 : PI_F - pq2;
        const float t2 = (an2 - THETA_T) * INV_SIG;
        gsum = fmaf(__expf(-0.5f * t2 * t2), (float)v2, gsum);
    }
    RED(gsum)
#undef RED

    const float cn = (float)total;
    const float invnb = 1.f / fmaxf(cn, 1.f);
    const float q2v = invnb * sqrtf(2.5132741228718345f * S2);  // 4pi/5
    const float q4v = invnb * sqrtf(1.3962634015954636f * S4);  // 4pi/9
    const float q6v = invnb * sqrtf(0.9666438933772774f * S6);  // 4pi/13
    const float tet = (2.f * gsum) / fmaxf(cn * (cn - 1.f), 1.f);

    if      (r == 0) out[0 * M + i] = cn;
    else if (r == 1) out[1 * M + i] = tet;
    else if (r == 2) out[2 * M + i] = q2v;
    else if (r == 3) out[3 * M + i] = q4v;
    else if (r == 4) out[4 * M + i] = q6v;
}

extern "C" void kernel_launch(void* const* d_in, const int* in_sizes, int n_in,
                              void* d_out, int out_size, void* d_ws, size_t ws_size,
                              hipStream_t stream) {
    const float* pos  = (const float*)d_in[0];
    const int*   aidx = (const int*)d_in[1];
    const int*   nidx = (const int*)d_in[2];
    const int*   vmsk = (const int*)d_in[3];
    float* out = (float*)d_out;
    const int M = in_sizes[1];
    const int grid = (M + APB - 1) / APB;
    op_kernel<<<grid, BLK, 0, stream>>>(pos, aidx, nidx, vmsk, out, M);
}